// Round 1
// baseline (772.234 us; speedup 1.0000x reference)
//
#include <hip/hip_runtime.h>
#include <hip/hip_bf16.h>

#define S 1024
#define DK 64
#define NKT (S / 64)
#define PITCH 72  // LDS row pitch (elems): 144B rows -> 16B-aligned b128 frag reads

typedef __attribute__((ext_vector_type(8))) short short8;
typedef __attribute__((ext_vector_type(4))) float f32x4;
typedef __attribute__((ext_vector_type(4))) unsigned short u16x4;

__device__ __forceinline__ unsigned short f2bf(float x) {
    unsigned int u = __float_as_uint(x);
    u += 0x7fffu + ((u >> 16) & 1u);  // RNE
    return (unsigned short)(u >> 16);
}
__device__ __forceinline__ float bf2f(unsigned short h) {
    return __uint_as_float(((unsigned int)h) << 16);
}

__global__ __launch_bounds__(256, 2)
void attn_fused(const float* __restrict__ Q, const float* __restrict__ K,
                const float* __restrict__ V, const int* __restrict__ mask,
                const float* __restrict__ tw, const float* __restrict__ du,
                float* __restrict__ out) {
    const int tid  = threadIdx.x;
    const int wave = tid >> 6;
    const int lane = tid & 63;
    const int l15  = lane & 15;
    const int quad = lane >> 4;

    const int bh = blockIdx.x >> 4;   // b*H+h, 0..63
    const int qt = blockIdx.x & 15;   // q-tile of 64 rows

    __shared__ unsigned short Kh[64 * PITCH];  // K tile bf16 hi, [key][kk]
    __shared__ unsigned short Kl[64 * PITCH];  // K tile bf16 lo
    __shared__ unsigned short Vh[64 * PITCH];  // V tile bf16 hi, TRANSPOSED [d][key]
    __shared__ unsigned short Vl[64 * PITCH];  // V tile bf16 lo, transposed
    __shared__ unsigned short Pb[64 * PITCH];  // P round-trip (wave-private rows)

    // ---- Q fragments (A layout: m=l15 row, k=quad*8+j), pre-scaled by 1/sqrt(64) ----
    short8 qh[2], ql[2];
    {
        const float* qg =
            Q + ((size_t)bh * S + (size_t)(qt * 64 + wave * 16 + l15)) * DK + quad * 8;
#pragma unroll
        for (int c = 0; c < 2; ++c) {
            float4 a = ((const float4*)(qg + c * 32))[0];
            float4 b = ((const float4*)(qg + c * 32))[1];
            float v[8] = {a.x, a.y, a.z, a.w, b.x, b.y, b.z, b.w};
#pragma unroll
            for (int j = 0; j < 8; ++j) {
                float x = v[j] * 0.125f;
                unsigned short h = f2bf(x);
                qh[c][j] = (short)h;
                ql[c][j] = (short)f2bf(x - bf2f(h));
            }
        }
    }

    // per-lane base pointers for its 4 C-layout rows (row = base + r)
    const size_t rowq = (size_t)bh * S + (size_t)(qt * 64 + wave * 16 + quad * 4);
    const int*   mp  = mask + rowq * S + l15;
    const float* twp = tw   + rowq * S + l15;
    const float* dup = du   + rowq * S + l15;

    float m_run[4], l_run[4];
    f32x4 Oacc[4];
#pragma unroll
    for (int r = 0; r < 4; ++r) { m_run[r] = -3.0e38f; l_run[r] = 0.f; }
#pragma unroll
    for (int t = 0; t < 4; ++t) Oacc[t] = (f32x4){0.f, 0.f, 0.f, 0.f};

#pragma unroll 1
    for (int kt = 0; kt < NKT; ++kt) {
        __syncthreads();  // previous iter's LDS reads done before restage
        // ---- stage K (row-major) and V (transposed) tiles as bf16 hi/lo ----
        {
            const int row = tid >> 2;         // 0..63 (key within tile)
            const int cp  = (tid & 3) << 4;   // 0,16,32,48 (col chunk)
            const float* kg = K + ((size_t)bh * S + (size_t)(kt * 64 + row)) * DK + cp;
            const float* vg = V + ((size_t)bh * S + (size_t)(kt * 64 + row)) * DK + cp;
#pragma unroll
            for (int i = 0; i < 4; ++i) {
                float4 kv = ((const float4*)kg)[i];
                float ke[4] = {kv.x, kv.y, kv.z, kv.w};
                u16x4 h4, l4;
#pragma unroll
                for (int j = 0; j < 4; ++j) {
                    unsigned short h = f2bf(ke[j]);
                    h4[j] = h;
                    l4[j] = f2bf(ke[j] - bf2f(h));
                }
                *(u16x4*)&Kh[row * PITCH + cp + i * 4] = h4;
                *(u16x4*)&Kl[row * PITCH + cp + i * 4] = l4;

                float4 vv = ((const float4*)vg)[i];
                float ve[4] = {vv.x, vv.y, vv.z, vv.w};
#pragma unroll
                for (int j = 0; j < 4; ++j) {
                    int d = cp + i * 4 + j;
                    unsigned short h = f2bf(ve[j]);
                    Vh[d * PITCH + row] = h;
                    Vl[d * PITCH + row] = f2bf(ve[j] - bf2f(h));
                }
            }
        }
        __syncthreads();

        // ---- scores = (Qh+Ql)*(Kh+Kl) ~ QhKh + QlKh + QhKl ----
        f32x4 sc[4];
#pragma unroll
        for (int t = 0; t < 4; ++t) {
            f32x4 acc = (f32x4){0.f, 0.f, 0.f, 0.f};
#pragma unroll
            for (int c = 0; c < 2; ++c) {
                const int ba = (t * 16 + l15) * PITCH + c * 32 + quad * 8;
                short8 bh8 = *(const short8*)&Kh[ba];
                short8 bl8 = *(const short8*)&Kl[ba];
                acc = __builtin_amdgcn_mfma_f32_16x16x32_bf16(qh[c], bh8, acc, 0, 0, 0);
                acc = __builtin_amdgcn_mfma_f32_16x16x32_bf16(ql[c], bh8, acc, 0, 0, 0);
                acc = __builtin_amdgcn_mfma_f32_16x16x32_bf16(qh[c], bl8, acc, 0, 0, 0);
            }
            sc[t] = acc;
        }

        // ---- mask + online softmax + time_weight*dropout ----
        float pw[4][4];   // [r][t]
        float alpha[4];
#pragma unroll
        for (int r = 0; r < 4; ++r) {
            const size_t off0 = (size_t)r * S + (size_t)(kt * 64);
            int mk[4]; float twv[4], duv[4];
#pragma unroll
            for (int t = 0; t < 4; ++t) {
                mk[t]  = mp [off0 + t * 16];
                twv[t] = twp[off0 + t * 16];
                duv[t] = dup[off0 + t * 16];
            }
            float s[4];
#pragma unroll
            for (int t = 0; t < 4; ++t) s[t] = mk[t] ? -1e9f : sc[t][r];
            float rm = fmaxf(fmaxf(s[0], s[1]), fmaxf(s[2], s[3]));
#pragma unroll
            for (int off = 8; off >= 1; off >>= 1) rm = fmaxf(rm, __shfl_xor(rm, off));
            const float mn = fmaxf(m_run[r], rm);
            const float al = __expf(m_run[r] - mn);
            float ps = 0.f;
#pragma unroll
            for (int t = 0; t < 4; ++t) {
                float pe = __expf(s[t] - mn);
                ps += pe;
                float w = (duv[t] >= 0.5f) ? (twv[t] + twv[t]) : 0.f;
                pw[r][t] = pe * w;
            }
#pragma unroll
            for (int off = 8; off >= 1; off >>= 1) ps += __shfl_xor(ps, off);
            l_run[r] = l_run[r] * al + ps;
            m_run[r] = mn;
            alpha[r] = al;
        }
#pragma unroll
        for (int t = 0; t < 4; ++t)
#pragma unroll
            for (int r = 0; r < 4; ++r) Oacc[t][r] *= alpha[r];

        // ---- P (C layout) -> LDS -> A layout, hi then lo (wave-private rows) ----
        unsigned short phs[4][4];
#pragma unroll
        for (int r = 0; r < 4; ++r)
#pragma unroll
            for (int t = 0; t < 4; ++t) {
                unsigned short h = f2bf(pw[r][t]);
                phs[r][t] = h;
                Pb[(wave * 16 + quad * 4 + r) * PITCH + t * 16 + l15] = h;
            }
        const int pab = (wave * 16 + l15) * PITCH + quad * 8;
        short8 ah[2], alf[2];
        ah[0] = *(const short8*)&Pb[pab];
        ah[1] = *(const short8*)&Pb[pab + 32];
#pragma unroll
        for (int r = 0; r < 4; ++r)
#pragma unroll
            for (int t = 0; t < 4; ++t)
                Pb[(wave * 16 + quad * 4 + r) * PITCH + t * 16 + l15] =
                    f2bf(pw[r][t] - bf2f(phs[r][t]));
        alf[0] = *(const short8*)&Pb[pab];
        alf[1] = *(const short8*)&Pb[pab + 32];

        // ---- O += (Ph+Pl)*(Vh+Vl) ~ PhVh + PlVh + PhVl ----
#pragma unroll
        for (int t = 0; t < 4; ++t) {
            f32x4 o = Oacc[t];
#pragma unroll
            for (int c = 0; c < 2; ++c) {
                const int vb = (t * 16 + l15) * PITCH + c * 32 + quad * 8;
                short8 vh8 = *(const short8*)&Vh[vb];
                short8 vl8 = *(const short8*)&Vl[vb];
                o = __builtin_amdgcn_mfma_f32_16x16x32_bf16(ah[c],  vh8, o, 0, 0, 0);
                o = __builtin_amdgcn_mfma_f32_16x16x32_bf16(alf[c], vh8, o, 0, 0, 0);
                o = __builtin_amdgcn_mfma_f32_16x16x32_bf16(ah[c],  vl8, o, 0, 0, 0);
            }
            Oacc[t] = o;
        }
    }

    // ---- epilogue: normalize by softmax denom, store fp32 ----
    const size_t ob =
        ((size_t)bh * S + (size_t)(qt * 64 + wave * 16 + quad * 4)) * DK + l15;
#pragma unroll
    for (int r = 0; r < 4; ++r) {
        const float inv = 1.0f / l_run[r];
#pragma unroll
        for (int t = 0; t < 4; ++t)
            out[ob + (size_t)r * DK + t * 16] = Oacc[t][r] * inv;
    }
}

extern "C" void kernel_launch(void* const* d_in, const int* in_sizes, int n_in,
                              void* d_out, int out_size, void* d_ws, size_t ws_size,
                              hipStream_t stream) {
    const float* Q  = (const float*)d_in[0];
    const float* K  = (const float*)d_in[1];
    const float* V  = (const float*)d_in[2];
    const int*   M  = (const int*)  d_in[3];
    const float* TW = (const float*)d_in[4];
    const float* DU = (const float*)d_in[5];
    float* out = (float*)d_out;

    dim3 grid(4 * 16 * (S / 64));  // (b,h) x q-tiles = 1024 blocks
    attn_fused<<<grid, dim3(256), 0, stream>>>(Q, K, V, M, TW, DU, out);
}

// Round 2
// 762.006 us; speedup vs baseline: 1.0134x; 1.0134x over previous
//
#include <hip/hip_runtime.h>
#include <hip/hip_bf16.h>

#define S 1024
#define DK 64
#define NKT (S / 64)
#define PITCH 72  // LDS row pitch (elems): 144B rows -> 16B-aligned b128 frag reads

typedef __attribute__((ext_vector_type(8))) short short8;
typedef __attribute__((ext_vector_type(4))) float f32x4;
typedef __attribute__((ext_vector_type(4))) unsigned short u16x4;

__device__ __forceinline__ unsigned short f2bf(float x) {
    unsigned int u = __float_as_uint(x);
    u += 0x7fffu + ((u >> 16) & 1u);  // RNE
    return (unsigned short)(u >> 16);
}
__device__ __forceinline__ float bf2f(unsigned short h) {
    return __uint_as_float(((unsigned int)h) << 16);
}

// Raw barrier: only drain LDS counter, leave global loads in flight.
// (__syncthreads() would emit s_waitcnt vmcnt(0) and kill cross-tile prefetch.)
#define LGKM_BARRIER()                                         \
    do {                                                       \
        asm volatile("s_waitcnt lgkmcnt(0)" ::: "memory");     \
        __builtin_amdgcn_s_barrier();                          \
    } while (0)

__global__ __launch_bounds__(256, 3)
void attn_fused(const float* __restrict__ Q, const float* __restrict__ K,
                const float* __restrict__ V, const int* __restrict__ mask,
                const float* __restrict__ tw, const float* __restrict__ du,
                float* __restrict__ out) {
    const int tid  = threadIdx.x;
    const int wave = tid >> 6;
    const int lane = tid & 63;
    const int l15  = lane & 15;
    const int quad = lane >> 4;

    const int bh = blockIdx.x >> 4;   // b*H+h, 0..63
    const int qt = blockIdx.x & 15;   // q-tile of 64 rows

    __shared__ unsigned short Kh[64 * PITCH];  // K tile bf16 hi, [key][kk]
    __shared__ unsigned short Kl[64 * PITCH];  // K tile bf16 lo
    __shared__ unsigned short Vh[64 * PITCH];  // V tile bf16 hi, TRANSPOSED [d][key]
    __shared__ unsigned short Vl[64 * PITCH];  // V tile bf16 lo, transposed
    __shared__ unsigned short Pb[64 * PITCH];  // P round-trip (wave-private rows)

    // ---- Q fragments (A layout: m=l15 row, k=quad*8+j), pre-scaled by 1/sqrt(64) ----
    short8 qh[2], ql[2];
    {
        const float* qg =
            Q + ((size_t)bh * S + (size_t)(qt * 64 + wave * 16 + l15)) * DK + quad * 8;
#pragma unroll
        for (int c = 0; c < 2; ++c) {
            float4 a = ((const float4*)(qg + c * 32))[0];
            float4 b = ((const float4*)(qg + c * 32))[1];
            float v[8] = {a.x, a.y, a.z, a.w, b.x, b.y, b.z, b.w};
#pragma unroll
            for (int j = 0; j < 8; ++j) {
                float x = v[j] * 0.125f;
                unsigned short h = f2bf(x);
                qh[c][j] = (short)h;
                ql[c][j] = (short)f2bf(x - bf2f(h));
            }
        }
    }

    // per-lane base pointers for its 4 C-layout rows (row = base + r)
    const size_t rowq = (size_t)bh * S + (size_t)(qt * 64 + wave * 16 + quad * 4);
    const int*   mp  = mask + rowq * S + l15;
    const float* twp = tw   + rowq * S + l15;
    const float* dup = du   + rowq * S + l15;

    // staging geometry (global->reg prefetch, reg->LDS after barrier)
    const int srow = tid >> 2;          // 0..63 (key within tile)
    const int scp  = (tid & 3) << 4;    // 0,16,32,48 (col chunk)
    const float* Kb = K + (size_t)bh * S * DK + (size_t)srow * DK + scp;
    const float* Vb = V + (size_t)bh * S * DK + (size_t)srow * DK + scp;

    // ---------- software-pipelined prefetch state ----------
    float4 Gk[4], Gv[4];                 // K/V staging tile (next)
    int    mkv[4][4];                    // side tensors (next): [r][t]
    float  twv[4][4], duv[4][4];

    // NOTE: issue order must match consumption order (vmcnt is in-order):
    // G(kt), side(kt), G(kt+1), side(kt+1), ...
#define ISSUE_KV(KT)                                                         \
    do {                                                                     \
        const float* kg_ = Kb + (size_t)(KT) * 64 * DK;                      \
        const float* vg_ = Vb + (size_t)(KT) * 64 * DK;                      \
        _Pragma("unroll") for (int i_ = 0; i_ < 4; ++i_) {                   \
            Gk[i_] = ((const float4*)kg_)[i_];                               \
            Gv[i_] = ((const float4*)vg_)[i_];                               \
        }                                                                    \
    } while (0)

#define ISSUE_SIDE(KT)                                                      \
    do {                                                                    \
        _Pragma("unroll") for (int r_ = 0; r_ < 4; ++r_) {                  \
            const size_t o_ = (size_t)r_ * S + (size_t)((KT) * 64);         \
            _Pragma("unroll") for (int t_ = 0; t_ < 4; ++t_) {              \
                mkv[r_][t_] = mp [o_ + t_ * 16];                            \
                twv[r_][t_] = twp[o_ + t_ * 16];                            \
                duv[r_][t_] = dup[o_ + t_ * 16];                            \
            }                                                               \
        }                                                                   \
    } while (0)

    ISSUE_KV(0);
    ISSUE_SIDE(0);

    float m_run[4], l_run[4];
    f32x4 Oacc[4];
#pragma unroll
    for (int r = 0; r < 4; ++r) { m_run[r] = -3.0e38f; l_run[r] = 0.f; }
#pragma unroll
    for (int t = 0; t < 4; ++t) Oacc[t] = (f32x4){0.f, 0.f, 0.f, 0.f};

#pragma unroll 1
    for (int kt = 0; kt < NKT; ++kt) {
        // ---- stage prefetched K/V regs -> LDS as bf16 hi/lo ----
        LGKM_BARRIER();  // previous iter's LDS frag reads done before restage
        {
#pragma unroll
            for (int i = 0; i < 4; ++i) {
                float ke[4] = {Gk[i].x, Gk[i].y, Gk[i].z, Gk[i].w};
                u16x4 h4, l4;
#pragma unroll
                for (int j = 0; j < 4; ++j) {
                    unsigned short h = f2bf(ke[j]);
                    h4[j] = h;
                    l4[j] = f2bf(ke[j] - bf2f(h));
                }
                *(u16x4*)&Kh[srow * PITCH + scp + i * 4] = h4;
                *(u16x4*)&Kl[srow * PITCH + scp + i * 4] = l4;

                float ve[4] = {Gv[i].x, Gv[i].y, Gv[i].z, Gv[i].w};
#pragma unroll
                for (int j = 0; j < 4; ++j) {
                    int d = scp + i * 4 + j;
                    unsigned short h = f2bf(ve[j]);
                    Vh[d * PITCH + srow] = h;
                    Vl[d * PITCH + srow] = f2bf(ve[j] - bf2f(h));
                }
            }
        }
        LGKM_BARRIER();

        // ---- scores = (Qh+Ql)*(Kh+Kl) ~ QhKh + QlKh + QhKl ----
        f32x4 sc[4];
#pragma unroll
        for (int t = 0; t < 4; ++t) {
            f32x4 acc = (f32x4){0.f, 0.f, 0.f, 0.f};
#pragma unroll
            for (int c = 0; c < 2; ++c) {
                const int ba = (t * 16 + l15) * PITCH + c * 32 + quad * 8;
                short8 bh8 = *(const short8*)&Kh[ba];
                short8 bl8 = *(const short8*)&Kl[ba];
                acc = __builtin_amdgcn_mfma_f32_16x16x32_bf16(qh[c], bh8, acc, 0, 0, 0);
                acc = __builtin_amdgcn_mfma_f32_16x16x32_bf16(ql[c], bh8, acc, 0, 0, 0);
                acc = __builtin_amdgcn_mfma_f32_16x16x32_bf16(qh[c], bl8, acc, 0, 0, 0);
            }
            sc[t] = acc;
        }

        // ---- issue next tile's K/V loads (before side consume: keeps vmcnt order) ----
        const int ktn = (kt + 1) & (NKT - 1);  // wraps to 0 on last iter (valid addrs)
        ISSUE_KV(ktn);

        // ---- mask + online softmax + time_weight*dropout (consumes side regs) ----
        float pw[4][4];   // [r][t]
        float alpha[4];
#pragma unroll
        for (int r = 0; r < 4; ++r) {
            float s[4];
#pragma unroll
            for (int t = 0; t < 4; ++t) s[t] = mkv[r][t] ? -1e9f : sc[t][r];
            float rm = fmaxf(fmaxf(s[0], s[1]), fmaxf(s[2], s[3]));
#pragma unroll
            for (int off = 8; off >= 1; off >>= 1) rm = fmaxf(rm, __shfl_xor(rm, off));
            const float mn = fmaxf(m_run[r], rm);
            const float al = __expf(m_run[r] - mn);
            float ps = 0.f;
#pragma unroll
            for (int t = 0; t < 4; ++t) {
                float pe = __expf(s[t] - mn);
                ps += pe;
                float w = (duv[r][t] >= 0.5f) ? (twv[r][t] + twv[r][t]) : 0.f;
                pw[r][t] = pe * w;
            }
#pragma unroll
            for (int off = 8; off >= 1; off >>= 1) ps += __shfl_xor(ps, off);
            l_run[r] = l_run[r] * al + ps;
            m_run[r] = mn;
            alpha[r] = al;
        }

        // ---- issue next tile's side loads (after consume; WAR on regs is fine) ----
        ISSUE_SIDE(ktn);

#pragma unroll
        for (int t = 0; t < 4; ++t)
#pragma unroll
            for (int r = 0; r < 4; ++r) Oacc[t][r] *= alpha[r];

        // ---- P (C layout) -> LDS -> A layout, hi then lo (wave-private rows) ----
        unsigned short phs[4][4];
#pragma unroll
        for (int r = 0; r < 4; ++r)
#pragma unroll
            for (int t = 0; t < 4; ++t) {
                unsigned short h = f2bf(pw[r][t]);
                phs[r][t] = h;
                Pb[(wave * 16 + quad * 4 + r) * PITCH + t * 16 + l15] = h;
            }
        const int pab = (wave * 16 + l15) * PITCH + quad * 8;
        short8 ah[2], alf[2];
        ah[0] = *(const short8*)&Pb[pab];
        ah[1] = *(const short8*)&Pb[pab + 32];
#pragma unroll
        for (int r = 0; r < 4; ++r)
#pragma unroll
            for (int t = 0; t < 4; ++t)
                Pb[(wave * 16 + quad * 4 + r) * PITCH + t * 16 + l15] =
                    f2bf(pw[r][t] - bf2f(phs[r][t]));
        alf[0] = *(const short8*)&Pb[pab];
        alf[1] = *(const short8*)&Pb[pab + 32];

        // ---- O += (Ph+Pl)*(Vh+Vl) ~ PhVh + PlVh + PhVl ----
#pragma unroll
        for (int t = 0; t < 4; ++t) {
            f32x4 o = Oacc[t];
#pragma unroll
            for (int c = 0; c < 2; ++c) {
                const int vb = (t * 16 + l15) * PITCH + c * 32 + quad * 8;
                short8 vh8 = *(const short8*)&Vh[vb];
                short8 vl8 = *(const short8*)&Vl[vb];
                o = __builtin_amdgcn_mfma_f32_16x16x32_bf16(ah[c],  vh8, o, 0, 0, 0);
                o = __builtin_amdgcn_mfma_f32_16x16x32_bf16(alf[c], vh8, o, 0, 0, 0);
                o = __builtin_amdgcn_mfma_f32_16x16x32_bf16(ah[c],  vl8, o, 0, 0, 0);
            }
            Oacc[t] = o;
        }
    }

    // ---- epilogue: normalize by softmax denom, store fp32 ----
    const size_t ob =
        ((size_t)bh * S + (size_t)(qt * 64 + wave * 16 + quad * 4)) * DK + l15;
#pragma unroll
    for (int r = 0; r < 4; ++r) {
        const float inv = 1.0f / l_run[r];
#pragma unroll
        for (int t = 0; t < 4; ++t)
            out[ob + (size_t)r * DK + t * 16] = Oacc[t][r] * inv;
    }
}

extern "C" void kernel_launch(void* const* d_in, const int* in_sizes, int n_in,
                              void* d_out, int out_size, void* d_ws, size_t ws_size,
                              hipStream_t stream) {
    const float* Q  = (const float*)d_in[0];
    const float* K  = (const float*)d_in[1];
    const float* V  = (const float*)d_in[2];
    const int*   M  = (const int*)  d_in[3];
    const float* TW = (const float*)d_in[4];
    const float* DU = (const float*)d_in[5];
    float* out = (float*)d_out;

    dim3 grid(4 * 16 * (S / 64));  // (b,h) x q-tiles = 1024 blocks
    attn_fused<<<grid, dim3(256), 0, stream>>>(Q, K, V, M, TW, DU, out);
}